// Round 12
// baseline (286.073 us; speedup 1.0000x reference)
//
#include <hip/hip_runtime.h>
#include <hip/hip_bf16.h>

typedef __attribute__((ext_vector_type(8))) __bf16 bf16x8;
typedef __attribute__((ext_vector_type(4))) float f32x4;

#define NN 100000
#define NE 1600000
#define NBK 6250          // buckets of 16 nodes (NN/16)
#define SCB 25            // ceil(NBK/256) scan blocks
#define ECHUNK 200000     // NE/8 edges per chunk-group
#define MAXE 2048         // LDS edge-slice capacity per pass

__device__ __forceinline__ float bflo(unsigned w) { return __uint_as_float(w << 16); }
__device__ __forceinline__ float bfhi(unsigned w) { return __uint_as_float(w & 0xffff0000u); }

// ---------------- converts + cnt8 zeroing (memset folded in) ----------------
__global__ void convert_kernel(const float* __restrict__ W1, const float* __restrict__ W2,
                               __bf16* __restrict__ W1T, __bf16* __restrict__ W2T,
                               const float4* __restrict__ x4, uint2* __restrict__ xb,
                               int* __restrict__ cnt8) {
    int tid = blockIdx.x * 256 + threadIdx.x;
    if (tid < 128 * 256) {
        int k1 = tid >> 8, n1 = tid & 255;             // W1 is [128][256]
        W1T[n1 * 128 + k1] = (__bf16)W1[tid];
        int k2 = tid >> 7, n2 = tid & 127;             // W2 is [256][128]
        W2T[n2 * 256 + k2] = (__bf16)W2[tid];
    } else {
        int i = tid - 128 * 256;
        if (i < NN * 32) {                             // n4 = NN*128/4
            float4 v = x4[i];
            __bf16 b0 = (__bf16)v.x, b1 = (__bf16)v.y, b2 = (__bf16)v.z, b3 = (__bf16)v.w;
            uint2 o;
            o.x = (unsigned)*(unsigned short*)&b0 | ((unsigned)*(unsigned short*)&b1 << 16);
            o.y = (unsigned)*(unsigned short*)&b2 | ((unsigned)*(unsigned short*)&b3 << 16);
            xb[i] = o;
        } else {
            int j = i - NN * 32;
            if (j < 8 * NBK) cnt8[j] = 0;
        }
    }
}

// ---------------- bucket-granular hist (chunk-partitioned, each edge read once) --------------
__global__ void hist_bucket8(const int* __restrict__ edst, int* __restrict__ cnt8) {
    int grp  = blockIdx.x & 7;
    int blk  = blockIdx.x >> 3;
    int nblk = gridDim.x >> 3;
    int* my = cnt8 + grp * NBK;
    int lo = grp * ECHUNK, hi = lo + ECHUNK;
    if (hi > NE) hi = NE;
    for (int e = lo + blk * 256 + threadIdx.x; e < hi; e += nblk * 256)
        atomicAdd(&my[edst[e] >> 4], 1);
}

// ---------------- hierarchical scan over NBK bucket totals (3 tiny kernels) ------------------
__global__ void scan_bs(const int* __restrict__ cnt8, int* __restrict__ bsum) {
    __shared__ int sm[256];
    int i = blockIdx.x * 256 + threadIdx.x;
    int v = 0;
    if (i < NBK) {
#pragma unroll
        for (int g = 0; g < 8; ++g) v += cnt8[g * NBK + i];
    }
    sm[threadIdx.x] = v;
    __syncthreads();
    for (int s = 128; s > 0; s >>= 1) {
        if (threadIdx.x < s) sm[threadIdx.x] += sm[threadIdx.x + s];
        __syncthreads();
    }
    if (threadIdx.x == 0) bsum[blockIdx.x] = sm[0];
}

__global__ void scan_p(const int* __restrict__ bsum, int* __restrict__ boff) {
    int t = threadIdx.x;                 // one wave (64 >= SCB)
    int v = (t < SCB) ? bsum[t] : 0;
    int s = v;
#pragma unroll
    for (int off = 1; off < 64; off <<= 1) {
        int u = __shfl_up(s, off);
        if (t >= off) s += u;
    }
    if (t < SCB) boff[t] = s - v;        // exclusive
}

__global__ void scan_wo(const int* __restrict__ cnt8, const int* __restrict__ boff,
                        int* __restrict__ bucket_off, int* __restrict__ cursor8) {
    __shared__ int sm[256];
    int t = threadIdx.x;
    int i = blockIdx.x * 256 + t;
    int c[8]; int tot = 0;
    if (i < NBK) {
#pragma unroll
        for (int g = 0; g < 8; ++g) { c[g] = cnt8[g * NBK + i]; tot += c[g]; }
    }
    sm[t] = tot; __syncthreads();
    for (int off = 1; off < 256; off <<= 1) {
        int add = (t >= off) ? sm[t - off] : 0;
        __syncthreads();
        sm[t] += add;
        __syncthreads();
    }
    int excl = sm[t] - tot + boff[blockIdx.x];
    if (i < NBK) {
        bucket_off[i] = excl;
        int run = excl;
#pragma unroll
        for (int g = 0; g < 8; ++g) { cursor8[g * NBK + i] = run; run += c[g]; }
    }
    if (i == 0) bucket_off[NBK] = NE;
}

// ---------------- chunk-partitioned binned scatter (each edge read once) ---------------------
// 6250 write streams per group (~400KB hot lines, L2-resident -> lines fill before writeback).
// pairs[pos] = {(src<<8)|(dst&15), val_bits}
__global__ void reorder_bucket8(const int* __restrict__ esrc, const int* __restrict__ edst,
                                const float* __restrict__ ev,
                                int* cursor8, int2* __restrict__ pairs) {
    int grp  = blockIdx.x & 7;
    int blk  = blockIdx.x >> 3;
    int nblk = gridDim.x >> 3;
    int* cur = cursor8 + grp * NBK;
    int lo = grp * ECHUNK, hi = lo + ECHUNK;
    if (hi > NE) hi = NE;
    for (int e = lo + blk * 256 + threadIdx.x; e < hi; e += nblk * 256) {
        int d = edst[e];
        int s = esrc[e];
        float v = ev[e];
        int pos = atomicAdd(&cur[d >> 4], 1);
        int2 p; p.x = (s << 8) | (d & 15); p.y = __float_as_int(v);
        pairs[pos] = p;
    }
}

// ---------------- fused LDS-sort + gather: one block per 16-node bucket ----------------
// 1024 threads = 16 waves; wave w owns node b*16+w. Slice loaded to LDS once,
// node-sorted in LDS (count/scan/permute), then gathered with half-wave split.
__global__ __launch_bounds__(1024) void sort_gather_kernel(const unsigned* __restrict__ xb,
                                                           const int* __restrict__ bucket_off,
                                                           const int2* __restrict__ pairs,
                                                           const float* __restrict__ eps,
                                                           uint2* __restrict__ AXb) {
    __shared__ int2 raw[MAXE];
    __shared__ int2 srt[MAXE];
    __shared__ int rcnt[16], rofs[16], rcur[16];

    const int t = threadIdx.x;
    const int b = blockIdx.x;
    const int beg = bucket_off[b], end = bucket_off[b + 1];
    const int wave = t >> 6, lane = t & 63;
    const unsigned hw = lane >> 5, l32 = lane & 31u;
    const char* xbase = (const char*)xb + l32 * 8;

    float a0 = 0.f, a1 = 0.f, a2 = 0.f, a3 = 0.f;

    for (int cbeg = beg; cbeg < end; cbeg += MAXE) {
        int m = end - cbeg; if (m > MAXE) m = MAXE;
        if (t < 16) rcnt[t] = 0;
        __syncthreads();
        for (int i = t; i < m; i += 1024) {
            int2 p = pairs[cbeg + i];
            raw[i] = p;
            atomicAdd(&rcnt[p.x & 15], 1);
        }
        __syncthreads();
        if (t == 0) {
            int run = 0;
#pragma unroll
            for (int r = 0; r < 16; ++r) { rofs[r] = run; rcur[r] = run; run += rcnt[r]; }
        }
        __syncthreads();
        for (int i = t; i < m; i += 1024) {
            int2 p = raw[i];
            int pos = atomicAdd(&rcur[p.x & 15], 1);
            int2 q; q.x = p.x & 0xffffff00; q.y = p.y;  // {src byte-offset, val bits}
            srt[pos] = q;
        }
        __syncthreads();

        // gather: wave's node slice [rofs, rofs+rcnt) of srt; half-waves interleave
        {
            const int je = rofs[wave] + rcnt[wave];
            int j = rofs[wave] + (int)hw;
            for (; j + 6 < je; j += 8) {               // 4 edges per half per iter
                int2 e0 = srt[j], e1 = srt[j + 2], e2 = srt[j + 4], e3 = srt[j + 6];
                uint2 w0 = *(const uint2*)(xbase + e0.x);
                uint2 w1 = *(const uint2*)(xbase + e1.x);
                uint2 w2 = *(const uint2*)(xbase + e2.x);
                uint2 w3 = *(const uint2*)(xbase + e3.x);
                float v0 = __int_as_float(e0.y), v1 = __int_as_float(e1.y);
                float v2 = __int_as_float(e2.y), v3 = __int_as_float(e3.y);
                a0 = fmaf(v0, bflo(w0.x), a0); a1 = fmaf(v0, bfhi(w0.x), a1);
                a2 = fmaf(v0, bflo(w0.y), a2); a3 = fmaf(v0, bfhi(w0.y), a3);
                a0 = fmaf(v1, bflo(w1.x), a0); a1 = fmaf(v1, bfhi(w1.x), a1);
                a2 = fmaf(v1, bflo(w1.y), a2); a3 = fmaf(v1, bfhi(w1.y), a3);
                a0 = fmaf(v2, bflo(w2.x), a0); a1 = fmaf(v2, bfhi(w2.x), a1);
                a2 = fmaf(v2, bflo(w2.y), a2); a3 = fmaf(v2, bfhi(w2.y), a3);
                a0 = fmaf(v3, bflo(w3.x), a0); a1 = fmaf(v3, bfhi(w3.x), a1);
                a2 = fmaf(v3, bflo(w3.y), a2); a3 = fmaf(v3, bfhi(w3.y), a3);
            }
            for (; j < je; j += 2) {
                int2 e0 = srt[j];
                uint2 w0 = *(const uint2*)(xbase + e0.x);
                float v0 = __int_as_float(e0.y);
                a0 = fmaf(v0, bflo(w0.x), a0); a1 = fmaf(v0, bfhi(w0.x), a1);
                a2 = fmaf(v0, bflo(w0.y), a2); a3 = fmaf(v0, bfhi(w0.y), a3);
            }
        }
        __syncthreads();   // protect LDS before next chunk overwrites
    }

    // combine half-wave partials, add self-loop, store bf16 AX row
    a0 += __shfl_xor(a0, 32); a1 += __shfl_xor(a1, 32);
    a2 += __shfl_xor(a2, 32); a3 += __shfl_xor(a3, 32);
    if (hw == 0) {
        const int n = b * 16 + wave;
        uint2 ws = *(const uint2*)(xbase + (size_t)n * 256);
        float sc = 1.0f + eps[0];
        a0 = fmaf(sc, bflo(ws.x), a0); a1 = fmaf(sc, bfhi(ws.x), a1);
        a2 = fmaf(sc, bflo(ws.y), a2); a3 = fmaf(sc, bfhi(ws.y), a3);
        __bf16 b0 = (__bf16)a0, b1 = (__bf16)a1, b2 = (__bf16)a2, b3 = (__bf16)a3;
        uint2 o;
        o.x = (unsigned)*(unsigned short*)&b0 | ((unsigned)*(unsigned short*)&b1 << 16);
        o.y = (unsigned)*(unsigned short*)&b2 | ((unsigned)*(unsigned short*)&b3 << 16);
        AXb[(size_t)n * 32 + l32] = o;
    }
}

// ---------------- fallback path (atomic scatter, fp32 AX in d_out) ----------------
__global__ void init_ax_kernel(const float4* __restrict__ x, float4* __restrict__ AX,
                               const float* __restrict__ eps, int n4) {
    int i = blockIdx.x * blockDim.x + threadIdx.x;
    if (i >= n4) return;
    float s = 1.0f + eps[0];
    float4 v = x[i];
    v.x *= s; v.y *= s; v.z *= s; v.w *= s;
    AX[i] = v;
}

__global__ void scatter_kernel(const float2* __restrict__ x2, const float* __restrict__ ev,
                               const int* __restrict__ esrc, const int* __restrict__ edst,
                               float* AX) {
    unsigned gid = blockIdx.x * 256u + threadIdx.x;
    unsigned e = gid >> 6;
    unsigned lane = gid & 63u;
    if (e >= NE) return;
    float v = ev[e];
    int s = esrc[e], d = edst[e];
    float2 xv = x2[(size_t)s * 64 + lane];
    float* dstp = AX + (size_t)d * 128 + lane * 2;
    atomicAdd(dstp,     v * xv.x);
    atomicAdd(dstp + 1, v * xv.y);
}

// ---------------- fused 2-layer MLP: out = relu(A@W1+b1)@W2+b2 ----------------
template <typename AT>
__global__ __launch_bounds__(256) void mlp_kernel(const AT* A,
                                                  const __bf16* __restrict__ W1T,
                                                  const __bf16* __restrict__ W2T,
                                                  const float* __restrict__ b1,
                                                  const float* __restrict__ b2,
                                                  float* out) {
    __shared__ __bf16 Hl[64][264];

    const int wave = threadIdx.x >> 6;
    const int lane = threadIdx.x & 63;
    const int l15  = lane & 15;
    const int lhi  = lane >> 4;
    const int rowbase = blockIdx.x * 64;

    f32x4 acc1[4][4] = {};
#pragma unroll
    for (int ks = 0; ks < 4; ++ks) {
        const int k0 = ks * 32 + lhi * 8;
        bf16x8 am[4], bn[4];
#pragma unroll
        for (int mt = 0; mt < 4; ++mt) {
            int row = rowbase + mt * 16 + l15;
            if (row >= NN) row = NN - 1;
            if constexpr (__is_same(AT, __bf16)) {
                am[mt] = *(const bf16x8*)(A + (size_t)row * 128 + k0);
            } else {
                const float4* ap = (const float4*)(A + (size_t)row * 128 + k0);
                float4 f0 = ap[0], f1 = ap[1];
                bf16x8 a;
                a[0]=(__bf16)f0.x; a[1]=(__bf16)f0.y; a[2]=(__bf16)f0.z; a[3]=(__bf16)f0.w;
                a[4]=(__bf16)f1.x; a[5]=(__bf16)f1.y; a[6]=(__bf16)f1.z; a[7]=(__bf16)f1.w;
                am[mt] = a;
            }
        }
#pragma unroll
        for (int nt = 0; nt < 4; ++nt) {
            int n = wave * 64 + nt * 16 + l15;
            bn[nt] = *(const bf16x8*)(W1T + (size_t)n * 128 + k0);
        }
#pragma unroll
        for (int mt = 0; mt < 4; ++mt)
#pragma unroll
            for (int nt = 0; nt < 4; ++nt)
                acc1[mt][nt] = __builtin_amdgcn_mfma_f32_16x16x32_bf16(am[mt], bn[nt], acc1[mt][nt], 0, 0, 0);
    }

#pragma unroll
    for (int nt = 0; nt < 4; ++nt) {
        int n = wave * 64 + nt * 16 + l15;
        float bias = b1[n];
#pragma unroll
        for (int mt = 0; mt < 4; ++mt)
#pragma unroll
            for (int r = 0; r < 4; ++r) {
                float h = acc1[mt][nt][r] + bias;
                Hl[mt * 16 + lhi * 4 + r][n] = (__bf16)fmaxf(h, 0.0f);
            }
    }
    __syncthreads();

    f32x4 acc2[4][2] = {};
#pragma unroll
    for (int ks = 0; ks < 8; ++ks) {
        const int k0 = ks * 32 + lhi * 8;
        bf16x8 ha[4], wb[2];
#pragma unroll
        for (int mt = 0; mt < 4; ++mt)
            ha[mt] = *(const bf16x8*)(&Hl[mt * 16 + l15][k0]);
#pragma unroll
        for (int nt = 0; nt < 2; ++nt) {
            int n = wave * 32 + nt * 16 + l15;
            wb[nt] = *(const bf16x8*)(W2T + (size_t)n * 256 + k0);
        }
#pragma unroll
        for (int mt = 0; mt < 4; ++mt)
#pragma unroll
            for (int nt = 0; nt < 2; ++nt)
                acc2[mt][nt] = __builtin_amdgcn_mfma_f32_16x16x32_bf16(ha[mt], wb[nt], acc2[mt][nt], 0, 0, 0);
    }

#pragma unroll
    for (int nt = 0; nt < 2; ++nt) {
        int n = wave * 32 + nt * 16 + l15;
        float bias = b2[n];
#pragma unroll
        for (int mt = 0; mt < 4; ++mt)
#pragma unroll
            for (int r = 0; r < 4; ++r) {
                int row = rowbase + mt * 16 + lhi * 4 + r;
                if (row < NN) out[(size_t)row * 128 + n] = acc2[mt][nt][r] + bias;
            }
    }
}

extern "C" void kernel_launch(void* const* d_in, const int* in_sizes, int n_in,
                              void* d_out, int out_size, void* d_ws, size_t ws_size,
                              hipStream_t stream) {
    const float* x    = (const float*)d_in[0];
    const float* ev   = (const float*)d_in[1];
    const float* W1   = (const float*)d_in[2];
    const float* b1   = (const float*)d_in[3];
    const float* W2   = (const float*)d_in[4];
    const float* b2   = (const float*)d_in[5];
    const float* eps  = (const float*)d_in[6];
    const int*   esrc = (const int*)d_in[7];
    const int*   edst = (const int*)d_in[8];
    float* out = (float*)d_out;

    char* ws = (char*)d_ws;
    size_t off = 0;
    auto alloc = [&](size_t bytes) { void* p = ws + off; off += (bytes + 511) & ~size_t(511); return p; };

    __bf16* W1T     = (__bf16*)alloc(128 * 256 * sizeof(__bf16));
    __bf16* W2T     = (__bf16*)alloc(128 * 256 * sizeof(__bf16));
    int* cnt8       = (int*)  alloc((size_t)8 * NBK * sizeof(int));
    int* bucket_off = (int*)  alloc((NBK + 1) * sizeof(int));
    int* cursor8    = (int*)  alloc((size_t)8 * NBK * sizeof(int));
    int* bsum       = (int*)  alloc(SCB * sizeof(int));
    int* boff       = (int*)  alloc(SCB * sizeof(int));
    int2* pairs     = (int2*) alloc((size_t)NE * sizeof(int2));
    unsigned* xb    = (unsigned*)alloc((size_t)NN * 64 * sizeof(unsigned));   // bf16 x
    unsigned* AXb   = (unsigned*)alloc((size_t)NN * 64 * sizeof(unsigned));   // bf16 AX
    bool csr_ok = (off <= ws_size);

    if (csr_ok) {
        int cblocks = (128 * 256 + NN * 32 + 8 * NBK + 255) / 256;   // weights + x + cnt8 zero
        convert_kernel<<<cblocks, 256, 0, stream>>>(W1, W2, W1T, W2T, (const float4*)x,
                                                    (uint2*)xb, cnt8);
        hist_bucket8<<<2048, 256, 0, stream>>>(edst, cnt8);
        scan_bs<<<SCB, 256, 0, stream>>>(cnt8, bsum);
        scan_p<<<1, 64, 0, stream>>>(bsum, boff);
        scan_wo<<<SCB, 256, 0, stream>>>(cnt8, boff, bucket_off, cursor8);
        reorder_bucket8<<<2048, 256, 0, stream>>>(esrc, edst, ev, cursor8, pairs);
        sort_gather_kernel<<<NBK, 1024, 0, stream>>>(xb, bucket_off, pairs, eps, (uint2*)AXb);
        int nblk = (NN + 63) / 64;
        mlp_kernel<__bf16><<<nblk, 256, 0, stream>>>((const __bf16*)AXb, W1T, W2T, b1, b2, out);
    } else {
        // fallback: atomic scatter path (fp32 AX in d_out)
        __bf16* W1Tf = (__bf16*)ws;
        __bf16* W2Tf = W1Tf + 128 * 256;
        convert_kernel<<<128, 256, 0, stream>>>(W1, W2, W1Tf, W2Tf, (const float4*)x,
                                                (uint2*)nullptr, (int*)nullptr);
        int n4 = NN * 128 / 4;
        init_ax_kernel<<<(n4 + 255) / 256, 256, 0, stream>>>((const float4*)x, (float4*)out, eps, n4);
        scatter_kernel<<<(NE * 64u) / 256u, 256, 0, stream>>>((const float2*)x, ev, esrc, edst, out);
        int nblk = (NN + 63) / 64;
        mlp_kernel<float><<<nblk, 256, 0, stream>>>(out, W1Tf, W2Tf, b1, b2, out);
    }
}